// Round 1
// 222.787 us; speedup vs baseline: 1.0538x; 1.0538x over previous
//
#include <hip/hip_runtime.h>
#include <hip/hip_bf16.h>

// Problem constants (from reference)
#define Hh    100
#define NN    1024     // B*L
#define BB    64
#define LL    16
#define EE    2048
#define NNODE 40000

#define BSPL  8        // b-loop split across blockIdx.y
#define BPB   (BB / BSPL)
#define PFR   8        // fragments per panel: f = t*4+ks, t in 0..1, ks in 0..3
#define PPAN  (PFR * 64 * 8)   // u16 per panel (4096)
#define GJ    4        // j-groups per wave (wave covers 64 embed rows)
#define EBS   104      // padded bf16 embed row stride (u16)

typedef unsigned short u16;
typedef __attribute__((ext_vector_type(8))) short short8;   // 8 bf16 = 4 VGPRs
typedef __attribute__((ext_vector_type(4))) float f32x4;    // MFMA C/D

__device__ __forceinline__ float bf2f(u16 u) {
    union { unsigned int i; float f; } v;
    v.i = ((unsigned int)u) << 16;
    return v.f;
}

__device__ __forceinline__ u16 f2bf(float f) {
    unsigned int x = __float_as_uint(f);
    unsigned int lsb = (x >> 16) & 1u;
    x += 0x7fffu + lsb;              // round-to-nearest-even
    return (u16)(x >> 16);
}

__device__ __forceinline__ float sigmoidf_(float x) {
    return 1.0f / (1.0f + expf(-x));
}

template <bool BF>
__device__ __forceinline__ float ldv(const void* p, size_t i) {
    if (BF) return bf2f(((const u16*)p)[i]);
    return ((const float*)p)[i];
}
__device__ __forceinline__ float ldvf(int flag, const void* p, size_t i) {
    return flag ? ldv<true>(p, i) : ldv<false>(p, i);
}

// ---------------------------------------------------------------------------
// k_cvt: per-block dtype self-detect + convert/transpose small float tensors
// to fp32 in ws. GRU weights interleaved as wC[k][j][8] = {wih_r,wih_z,wih_n,
// whh_r,whh_z,whh_n,pad,pad} so k_gru does 2 vector loads instead of 6 scalar.
// Also zero-inits the SD panel region (rows 8..15 stay zero).
template <bool BF>
__device__ void cvt_impl(int t,
                         const void* ew, const void* ggc, const void* wih, const void* whh,
                         const void* bih, const void* bhh, const void* W1w, const void* W1b,
                         const void* W2w, const void* W2b, const void* Wtw, const void* Wtb,
                         const void* qw, const void* qb, const void* W3w, const void* W3b,
                         float* __restrict__ W) {
    const void* src; int si; int doff; int di;
    if      (t <   2048) { src = ew;  si = t;          doff = 0;      di = si; }
    else if (t <  12048) { src = ggc; si = t - 2048;   doff = 2048;   di = si; }                      // row-major (k_gm)
    else if (t <  42048) { src = wih; si = t - 12048;  doff = 12048;  { int r = si / 100, k = si - r * 100; di = k * 800 + (r % 100) * 8 + r / 100; } }
    else if (t <  72048) { src = whh; si = t - 42048;  doff = 12048;  { int r = si / 100, k = si - r * 100; di = k * 800 + (r % 100) * 8 + 3 + r / 100; } }
    else if (t <  72348) { src = bih; si = t - 72048;  doff = 92048;  di = si; }
    else if (t <  72648) { src = bhh; si = t - 72348;  doff = 92352;  di = si; }
    else if (t <  82648) { src = W1w; si = t - 72648;  doff = 92656;  di = (si % 100) * 100 + si / 100; }   // T
    else if (t <  82748) { src = W1b; si = t - 82648;  doff = 102656; di = si; }
    else if (t <  92748) { src = W2w; si = t - 82748;  doff = 102768; di = (si % 100) * 100 + si / 100; }   // T
    else if (t <  92848) { src = W2b; si = t - 92748;  doff = 112768; di = si; }
    else if (t < 102848) { src = Wtw; si = t - 92848;  doff = 112880; di = (si % 100) * 100 + si / 100; }   // T
    else if (t < 102948) { src = Wtb; si = t - 102848; doff = 122880; di = si; }
    else if (t < 103048) { src = qw;  si = t - 102948; doff = 122992; di = si; }
    else if (t < 103049) { src = qb;  si = t - 103048; doff = 123104; di = si; }
    else if (t < 123049) { src = W3w; si = t - 103049; doff = 123120; di = (si % 200) * 100 + si / 200; }   // T
    else                 { src = W3b; si = t - 123049; doff = 143120; di = si; }
    W[doff + di] = ldv<BF>(src, si);
}

__global__ void __launch_bounds__(256) k_cvt(const void* embed_raw, int* __restrict__ flag,
                      const void* ew, const void* ggc, const void* wih, const void* whh,
                      const void* bih, const void* bhh, const void* W1w, const void* W1b,
                      const void* W2w, const void* W2b, const void* Wtw, const void* Wtb,
                      const void* qw, const void* qb, const void* W3w, const void* W3b,
                      float* __restrict__ W, u16* __restrict__ SD) {
    __shared__ int cnt;
    if (threadIdx.x == 0) cnt = 0;
    __syncthreads();
    int bad = 0;
    const u16* eb = (const u16*)embed_raw;
    for (int i = threadIdx.x; i < 4096; i += 256) {
        float v = bf2f(eb[i]);
        if (!(fabsf(v) <= 0.5f)) bad++;   // counts NaN too
    }
    if (bad) atomicAdd(&cnt, bad);
    __syncthreads();
    const bool bf = (cnt == 0);
    if (blockIdx.x == 0 && threadIdx.x == 0) flag[0] = bf ? 1 : 0;
    int t = blockIdx.x * 256 + threadIdx.x;
    if (t < 8192) ((unsigned int*)SD)[t] = 0u;   // zero SD panels (16384 u16)
    if (t >= 123149) return;
    if (bf) cvt_impl<true >(t, ew, ggc, wih, whh, bih, bhh, W1w, W1b, W2w, W2b, Wtw, Wtb, qw, qb, W3w, W3b, W);
    else    cvt_impl<false>(t, ew, ggc, wih, whh, bih, bhh, W1w, W1b, W2w, W2b, Wtw, Wtb, qw, qb, W3w, W3b, W);
}

// ---------------------------------------------------------------------------
// k_ecvt: one-time embed -> padded bf16 (row stride EBS=104, cols 100..103 = 0).
// Runs after k_cvt (reads flag). Each thread writes one u32 (2 cols).
__global__ void __launch_bounds__(256) k_ecvt(const int* __restrict__ flag,
                                              const void* __restrict__ embed,
                                              u16* __restrict__ EB) {
    const bool bf = (flag[0] != 0);
    int t = blockIdx.x * 256 + threadIdx.x;
    const int total = NNODE * (EBS / 2);          // 2,080,000 u32
    if (t >= total) return;
    int r = t / (EBS / 2), c2 = t - r * (EBS / 2);
    int k0 = c2 * 2;
    unsigned int w = 0;
    if (k0 + 1 < Hh) {
        if (bf) {
            w = *(const unsigned int*)&((const u16*)embed)[(size_t)r * Hh + k0];
        } else {
            float2 e2 = *(const float2*)&((const float*)embed)[(size_t)r * Hh + k0];
            w = (unsigned int)f2bf(e2.x) | ((unsigned int)f2bf(e2.y) << 16);
        }
    }
    ((unsigned int*)EB)[t] = w;
}

// ---------------------------------------------------------------------------
// k_gm: fused embed-gather + m = h0 @ ggc, plus agg zero-init.
__global__ void __launch_bounds__(256) k_gm(const int* __restrict__ flag,
                                            const int* __restrict__ x,
                                            const void* __restrict__ embed,
                                            const float* __restrict__ ggc_w,
                                            float* __restrict__ m,
                                            float* __restrict__ agg) {
    __shared__ float W[Hh * Hh];
    __shared__ float H[8 * Hh];
    const int tid = threadIdx.x;
    const int fl = flag[0];
    const int r0 = blockIdx.x * 8;
    for (int idx = tid; idx < Hh * Hh; idx += 256) W[idx] = ggc_w[idx];
    for (int idx = tid; idx < 8 * Hh; idx += 256) {
        int i = idx / Hh, j = idx - i * Hh;
        H[idx] = ldvf(fl, embed, (size_t)x[r0 + i] * Hh + j);
    }
    for (int idx = tid; idx < 8 * Hh; idx += 256) agg[r0 * Hh + idx] = 0.0f;
    __syncthreads();
    for (int idx = tid; idx < 8 * Hh; idx += 256) {
        int i = idx / Hh, j = idx - i * Hh;
        float acc = 0.0f;
#pragma unroll 4
        for (int k = 0; k < Hh; ++k) acc += H[i * Hh + k] * W[k * Hh + j];
        m[(r0 + i) * Hh + j] = acc;
    }
}

// agg[dst[e]] += ew[e] * m[src[e]]
__global__ void k_scatter(const int* __restrict__ ei, const float* __restrict__ ew,
                          const float* __restrict__ m, float* __restrict__ agg) {
    int t = blockIdx.x * 256 + threadIdx.x;
    if (t >= EE * Hh) return;
    int e = t / Hh, j = t - e * Hh;
    int src = ei[e], dst = ei[EE + e];
    atomicAdd(&agg[dst * Hh + j], ew[e] * m[src * Hh + j]);
}

// GRU cell: h0 re-gathered from embed. Interleaved weights wC[k][j][8] ->
// one float4 + one float2 per k (was 6 scalar strided loads).
__global__ void k_gru(const int* __restrict__ flag, const int* __restrict__ x,
                      const void* __restrict__ embed,
                      const float* __restrict__ agg,
                      const float* __restrict__ wC,
                      const float* __restrict__ bih, const float* __restrict__ bhh,
                      float* __restrict__ h1) {
    int t = blockIdx.x * 256 + threadIdx.x;
    if (t >= NN * Hh) return;
    int i = t / Hh, j = t - i * Hh;
    const int fl = flag[0];
    const size_t erow = (size_t)x[i] * Hh;
    const float* ar = agg + i * Hh;
    float s_ir = bih[j], s_iz = bih[j + Hh], s_in = bih[j + 2 * Hh];
    float s_hr = bhh[j], s_hz = bhh[j + Hh], s_hn = bhh[j + 2 * Hh];
    float h0j = 0.0f;
    const float* wbase = wC + j * 8;
    for (int k = 0; k < Hh; ++k) {
        float a = ar[k];
        float h = ldvf(fl, embed, erow + k);
        if (k == j) h0j = h;
        const float* wr = wbase + k * 800;
        float4 w0 = *(const float4*)wr;
        float2 w1 = *(const float2*)(wr + 4);
        s_ir += a * w0.x;
        s_iz += a * w0.y;
        s_in += a * w0.z;
        s_hr += h * w0.w;
        s_hz += h * w1.x;
        s_hn += h * w1.y;
    }
    float r = sigmoidf_(s_ir + s_hr);
    float z = sigmoidf_(s_iz + s_hz);
    float n = tanhf(s_in + r * s_hn);
    h1[t] = (1.0f - z) * n + z * h0j;
}

// ---------------------------------------------------------------------------
// k_att: per-session attention readout + swizzled P build (one block per b).
// P layout (per b): 8 frags, f = t*4+ks (t in 0..1), lane=quad*16+m ->
// logical P row t*16+m, col ks*32+quad*8+e. t=0 rows = VTs, t=1 rows = V.
// SD panel (per 8-b slice): 16x128 A-tile with row (b&7) = SH[b]; rows 8..15
// pre-zeroed by k_cvt. Same A-frag swizzle.
__global__ void __launch_bounds__(256) k_att(const float* __restrict__ h1,
                    const float* __restrict__ W1T, const float* __restrict__ W1b,
                    const float* __restrict__ W2T, const float* __restrict__ W2b,
                    const float* __restrict__ WtT, const float* __restrict__ Wtb,
                    const float* __restrict__ qw, const float* __restrict__ qb,
                    const float* __restrict__ W3T, const float* __restrict__ W3b,
                    u16* __restrict__ P, u16* __restrict__ SD) {
    __shared__ float V[LL * Hh];
    __shared__ float Q2[LL * Hh];
    __shared__ float VTs[LL * Hh];
    __shared__ float Q1[Hh];
    __shared__ float AL[LL];
    __shared__ float SG[Hh];
    __shared__ float SH[Hh];
    const int b = blockIdx.x, tid = threadIdx.x;
    for (int idx = tid; idx < LL * Hh; idx += 256) V[idx] = h1[b * LL * Hh + idx];
    __syncthreads();
    for (int idx = tid; idx < LL * Hh; idx += 256) {
        int i = idx / Hh, j = idx - i * Hh;
        float a2 = 0, at = 0;
        for (int k = 0; k < Hh; ++k) {
            float vk = V[i * Hh + k];
            a2 += vk * W2T[k * Hh + j];
            at += vk * WtT[k * Hh + j];
        }
        Q2[idx] = a2 + W2b[j];
        VTs[idx] = at + Wtb[j];
    }
    if (tid < Hh) {
        float a1 = 0;
        for (int k = 0; k < Hh; ++k) a1 += V[(LL - 1) * Hh + k] * W1T[k * Hh + tid];
        Q1[tid] = a1 + W1b[tid];
    }
    __syncthreads();
    if (tid < LL) {
        float acc = 0;
        for (int j = 0; j < Hh; ++j)
            acc += sigmoidf_(Q1[j] + Q2[tid * Hh + j]) * qw[j];
        AL[tid] = acc + qb[0];
    }
    __syncthreads();
    if (tid < Hh) {
        float acc = 0;
#pragma unroll
        for (int l = 0; l < LL; ++l) acc += AL[l] * V[l * Hh + tid];
        SG[tid] = acc;
    }
    __syncthreads();
    if (tid < Hh) {
        float acc = W3b[tid];
        for (int k = 0; k < Hh; ++k) acc += V[(LL - 1) * Hh + k] * W3T[k * Hh + tid];
        for (int k = 0; k < Hh; ++k) acc += SG[k] * W3T[(Hh + k) * Hh + tid];
        SH[tid] = acc;
    }
    __syncthreads();
    // Swizzled P write: 8 frags x 64 lanes x 8 elems
    for (int w = tid; w < PFR * 64; w += 256) {
        int f = w >> 6, lane = w & 63;
        int t = f >> 2, ks = f & 3;
        int mm = lane & 15, qq = lane >> 4;
        int col0 = ks * 32 + qq * 8;
        short8 t8;
#pragma unroll
        for (int e = 0; e < 8; ++e) {
            int col = col0 + e;
            float v = 0.0f;
            if (col < Hh) v = (t == 0) ? VTs[mm * Hh + col] : V[mm * Hh + col];
            t8[e] = (short)f2bf(v);
        }
        *(short8*)&P[((size_t)b * PFR + f) * 512 + lane * 8] = t8;
    }
    // SD write: this block owns row (b&7) of slice (b>>3); 128 u16 scattered.
    if (tid < 128) {
        int ks = tid >> 5, qq = (tid >> 3) & 3, e = tid & 7;
        int col = ks * 32 + qq * 8 + e;
        float v = (col < Hh) ? SH[col] : 0.0f;
        SD[(((size_t)(b >> 3) * 4 + ks) * 64 + qq * 16 + (b & 7)) * 8 + e] = f2bf(v);
    }
}

// ---------------------------------------------------------------------------
// k_score v7: SD panel removes the 1/16-useful t=2 MFMA tile (8 MFMAs once
// per block instead of 8 per iteration); GJ=4 j-groups per wave (256 embed
// rows/block) -> MFMA:ds_read ratio 4:1; embed fragments read from padded
// bf16 EB buffer (EMODE 1) with single aligned 16B loads. Register prefetch
// of next P panel overlaps the MFMAs; one barrier per iter. Max-free softmax.
__device__ __forceinline__ short8 load_efrag(const void* embed, bool bf, int j, int k0) {
    short8 v = {0, 0, 0, 0, 0, 0, 0, 0};
    if (j >= NNODE || k0 >= Hh) return v;
    if (bf) {
        const u16* row = (const u16*)embed + (size_t)j * Hh + k0;
        if (k0 + 8 <= Hh) {
            ushort4 a = *(const ushort4*)(row);
            ushort4 b = *(const ushort4*)(row + 4);
            v[0] = (short)a.x; v[1] = (short)a.y; v[2] = (short)a.z; v[3] = (short)a.w;
            v[4] = (short)b.x; v[5] = (short)b.y; v[6] = (short)b.z; v[7] = (short)b.w;
        } else {
            for (int e = 0; e < Hh - k0; ++e) v[e] = (short)row[e];
        }
    } else {
        const float* row = (const float*)embed + (size_t)j * Hh + k0;
        if (k0 + 8 <= Hh) {
            float4 a = *(const float4*)(row);
            float4 b = *(const float4*)(row + 4);
            v[0] = (short)f2bf(a.x); v[1] = (short)f2bf(a.y); v[2] = (short)f2bf(a.z); v[3] = (short)f2bf(a.w);
            v[4] = (short)f2bf(b.x); v[5] = (short)f2bf(b.y); v[6] = (short)f2bf(b.z); v[7] = (short)f2bf(b.w);
        } else {
            for (int e = 0; e < Hh - k0; ++e) v[e] = (short)f2bf(row[e]);
        }
    }
    return v;
}

template <int EMODE>
__global__ void __launch_bounds__(256) k_score(const int* __restrict__ flag,
                                               const void* __restrict__ embed,
                                               const u16* __restrict__ EB,
                                               const u16* __restrict__ P,
                                               const u16* __restrict__ SD,
                                               void* __restrict__ out) {
    __shared__ alignas(16) u16 sPan[2][PPAN];    // 2 x 8192 B
    const int jb = blockIdx.x * 256;
    const int b0 = blockIdx.y * BPB;
    const int slice = blockIdx.y;
    const int tid = threadIdx.x;
    const bool bf = (flag[0] != 0);
    const int wave = tid >> 6, lane = tid & 63;
    const int m = lane & 15, quad = lane >> 4;

    // B fragments: 4 groups of 16 embed rows per wave, loaded once.
    short8 Bf[GJ][4];
#pragma unroll
    for (int g = 0; g < GJ; ++g)
#pragma unroll
        for (int ks = 0; ks < 4; ++ks) {
            int j = jb + wave * 64 + g * 16 + m;
            if (EMODE) {
                short8 v = {0, 0, 0, 0, 0, 0, 0, 0};
                if (j < NNODE)
                    v = *(const short8*)&EB[(size_t)j * EBS + ks * 32 + quad * 8];
                Bf[g][ks] = v;
            } else {
                Bf[g][ks] = load_efrag(embed, bf, j, ks * 32 + quad * 8);
            }
        }

    // SD prologue: sd[b0+r][j] for all 8 b's of this slice, 16 MFMAs total.
    short8 Sf[4];
#pragma unroll
    for (int ks = 0; ks < 4; ++ks)
        Sf[ks] = *(const short8*)&SD[(((size_t)slice * 4 + ks) * 64 + lane) * 8];
    f32x4 accsd[GJ];
#pragma unroll
    for (int g = 0; g < GJ; ++g) {
        accsd[g] = (f32x4){0.0f, 0.0f, 0.0f, 0.0f};
#pragma unroll
        for (int ks = 0; ks < 4; ++ks)
            accsd[g] = __builtin_amdgcn_mfma_f32_16x16x32_bf16(Sf[ks], Bf[g][ks], accsd[g], 0, 0, 0);
    }

    // Preload panel b0 -> LDS buffer 0 (512 uint4)
    {
        const uint4* s4 = (const uint4*)(P + (size_t)b0 * PPAN);
        uint4 g0 = s4[tid], g1 = s4[tid + 256];
        uint4* d = (uint4*)sPan[0];
        d[tid] = g0; d[tid + 256] = g1;
    }
    __syncthreads();

    int cur = 0;
    for (int bi = 0; bi < BPB; ++bi) {
        const int b = b0 + bi;
        // Issue next-panel global loads (no wait — overlaps compute below)
        uint4 g0, g1;
        if (bi + 1 < BPB) {
            const uint4* s4 = (const uint4*)(P + (size_t)(b + 1) * PPAN);
            g0 = s4[tid]; g1 = s4[tid + 256];
        }

        const u16* sp = sPan[cur];
        f32x4 acc[GJ][2];
#pragma unroll
        for (int g = 0; g < GJ; ++g)
#pragma unroll
            for (int t = 0; t < 2; ++t)
                acc[g][t] = (f32x4){0.0f, 0.0f, 0.0f, 0.0f};
#pragma unroll
        for (int t = 0; t < 2; ++t) {
            short8 A0 = *(const short8*)&sp[(t * 4 + 0) * 512 + lane * 8];
            short8 A1 = *(const short8*)&sp[(t * 4 + 1) * 512 + lane * 8];
            short8 A2 = *(const short8*)&sp[(t * 4 + 2) * 512 + lane * 8];
            short8 A3 = *(const short8*)&sp[(t * 4 + 3) * 512 + lane * 8];
#pragma unroll
            for (int g = 0; g < GJ; ++g) {
                acc[g][t] = __builtin_amdgcn_mfma_f32_16x16x32_bf16(A0, Bf[g][0], acc[g][t], 0, 0, 0);
                acc[g][t] = __builtin_amdgcn_mfma_f32_16x16x32_bf16(A1, Bf[g][1], acc[g][t], 0, 0, 0);
                acc[g][t] = __builtin_amdgcn_mfma_f32_16x16x32_bf16(A2, Bf[g][2], acc[g][t], 0, 0, 0);
                acc[g][t] = __builtin_amdgcn_mfma_f32_16x16x32_bf16(A3, Bf[g][3], acc[g][t], 0, 0, 0);
            }
        }

        // Epilogue (max-free softmax). C/D layout: col=lane&15 (embed row
        // within group), row=quad*4+reg (P row) — m89/m91-verified.
#pragma unroll
        for (int g = 0; g < GJ; ++g) {
            float den = 0.0f, num = 0.0f;
#pragma unroll
            for (int r = 0; r < 4; ++r) {
                float p = __expf(acc[g][0][r]);
                den += p;
                num += p * acc[g][1][r];
            }
            den += __shfl_xor(den, 16); num += __shfl_xor(num, 16);
            den += __shfl_xor(den, 32); num += __shfl_xor(num, 32);
            // sd for (b, j=...+m) sits in lane (bi>>2)*16+m, reg bi&3.
            f32x4 s4v = accsd[g];
            int rr = bi & 3;
            float sdv = (rr == 0) ? s4v[0] : (rr == 1) ? s4v[1] : (rr == 2) ? s4v[2] : s4v[3];
            sdv = __shfl(sdv, ((bi >> 2) << 4) | m);
            if (quad == 0) {
                int j = jb + wave * 64 + g * 16 + m;
                if (j < NNODE) {
                    float z = sdv + num / den;
                    if (bf) ((u16*)out)[(size_t)b * NNODE + j] = f2bf(z);
                    else    ((float*)out)[(size_t)b * NNODE + j] = z;
                }
            }
        }

        // Commit prefetched panel to the other buffer (vmcnt wait lands here,
        // after compute) then single barrier.
        if (bi + 1 < BPB) {
            uint4* d = (uint4*)sPan[cur ^ 1];
            d[tid] = g0; d[tid + 256] = g1;
        }
        __syncthreads();
        cur ^= 1;
    }
}

extern "C" void kernel_launch(void* const* d_in, const int* in_sizes, int n_in,
                              void* d_out, int out_size, void* d_ws, size_t ws_size,
                              hipStream_t stream) {
    const int* x      = (const int*)d_in[0];
    const int* ei     = (const int*)d_in[1];
    const void* ew    = d_in[2];
    // d_in[3] batch: unused by reference
    const void* embed = d_in[4];
    const void* ggc   = d_in[5];
    const void* wih   = d_in[6];
    const void* whh   = d_in[7];
    const void* bih   = d_in[8];
    const void* bhh   = d_in[9];
    const void* W1w   = d_in[10];
    const void* W1b   = d_in[11];
    const void* W2w   = d_in[12];
    const void* W2b   = d_in[13];
    const void* Wtw   = d_in[14];
    const void* Wtb   = d_in[15];
    const void* qw    = d_in[16];
    const void* qb    = d_in[17];
    const void* W3w   = d_in[18];
    const void* W3b   = d_in[19];
    float* ws = (float*)d_ws;
    int* flag = (int*)d_ws;          // ws[0]

    // ws layout (floats):
    //   [0..64)              flag + pad
    //   [64..64+143232)      fp32 weight region W:
    //     ew_f   +0       (2048)
    //     ggc_f  +2048    (10000)   row-major
    //     wC     +12048   (80000)   [k][j][8] interleaved wih/whh
    //     bih    +92048   (300+pad)
    //     bhh    +92352   (300+pad)
    //     W1T    +92656   (10000)
    //     W1b    +102656  (100+pad)
    //     W2T    +102768  (10000)
    //     W2b    +112768  (100+pad)
    //     WtT    +112880  (10000)
    //     Wtb    +122880  (100+pad)
    //     qw     +122992  (100+pad)
    //     qb     +123104  (1+pad)
    //     W3T    +123120  (20000)
    //     W3b    +143120  (100+pad) -> 143232
    //   D = ws+143296, data region with overlays:
    //     m   = D+0       (102400)  written k_gm, read k_scatter (dead after)
    //     agg = D+102400  (102400)  zeroed k_gm, scatter-add, read k_gru (dead after)
    //     h1  = D+0       (102400)  overlays dead m; written k_gru, read k_att
    //     P   = (u16*)(D+102400)  131072 fl-equiv; overlays dead agg
    //     SD  = (u16*)(D+233472)  8192 fl-equiv (zeroed k_cvt, written k_att)
    //     EB  = (u16*)(D+241664)  2080000 fl-equiv padded bf16 embed (EMODE 1)
    float* W = ws + 64;
    float* ew_f  = W + 0;
    float* ggc_f = W + 2048;
    float* wC    = W + 12048;
    float* bih_f = W + 92048;
    float* bhh_f = W + 92352;
    float* W1T   = W + 92656;
    float* W1b_f = W + 102656;
    float* W2T   = W + 102768;
    float* W2b_f = W + 112768;
    float* WtT   = W + 112880;
    float* Wtb_f = W + 122880;
    float* qw_f  = W + 122992;
    float* qb_f  = W + 123104;
    float* W3T   = W + 123120;
    float* W3b_f = W + 143120;

    float* D     = ws + 143296;
    float* m     = D;
    float* agg   = D + 102400;
    float* h1    = D;                       // overlays dead m
    u16*   P     = (u16*)(D + 102400);      // overlays dead agg
    u16*   SDp   = (u16*)(D + 233472);
    u16*   EB    = (u16*)(D + 241664);

    const size_t need_bytes = (size_t)(143296 + 241664) * 4 + (size_t)NNODE * EBS * 2;
    const bool emode = (ws_size >= need_bytes);

    k_cvt    <<<dim3(482), dim3(256), 0, stream>>>(embed, flag, ew, ggc, wih, whh, bih, bhh,
                                                   W1w, W1b, W2w, W2b, Wtw, Wtb, qw, qb, W3w, W3b, W, SDp);
    if (emode)
        k_ecvt<<<dim3((NNODE * (EBS / 2) + 255) / 256), dim3(256), 0, stream>>>(flag, embed, EB);
    k_gm     <<<dim3(128), dim3(256), 0, stream>>>(flag, x, embed, ggc_f, m, agg);
    k_scatter<<<dim3(800), dim3(256), 0, stream>>>(ei, ew_f, m, agg);
    k_gru    <<<dim3(400), dim3(256), 0, stream>>>(flag, x, embed, agg, wC, bih_f, bhh_f, h1);
    k_att    <<<dim3(64),  dim3(256), 0, stream>>>(h1, W1T, W1b_f, W2T, W2b_f, WtT, Wtb_f,
                                                   qw_f, qb_f, W3T, W3b_f, P, SDp);
    if (emode)
        k_score<1><<<dim3((NNODE + 255) / 256, BSPL), dim3(256), 0, stream>>>(flag, embed, EB, P, SDp, d_out);
    else
        k_score<0><<<dim3((NNODE + 255) / 256, BSPL), dim3(256), 0, stream>>>(flag, embed, EB, P, SDp, d_out);
}

// Round 2
// 203.342 us; speedup vs baseline: 1.1545x; 1.0956x over previous
//
#include <hip/hip_runtime.h>
#include <hip/hip_bf16.h>

// Problem constants (from reference)
#define Hh    100
#define NN    1024     // B*L
#define BB    64
#define LL    16
#define EE    2048
#define NNODE 40000

#define BSPL  4        // b-loop split across blockIdx.y
#define BPB   (BB / BSPL)      // 16 b's per block == SD tile rows
#define PFR   8        // fragments per panel: f = t*4+ks, t in 0..1, ks in 0..3
#define PPAN  (PFR * 64 * 8)   // u16 per panel (4096)
#define GJ    4        // j-groups per wave (wave covers 64 embed rows)
#define EBS   104      // padded bf16 embed row stride (u16)
#define GRB   4        // rows per k_gruatt block

typedef unsigned short u16;
typedef __attribute__((ext_vector_type(8))) short short8;   // 8 bf16 = 4 VGPRs
typedef __attribute__((ext_vector_type(4))) float f32x4;    // MFMA C/D

__device__ __forceinline__ float bf2f(u16 u) {
    union { unsigned int i; float f; } v;
    v.i = ((unsigned int)u) << 16;
    return v.f;
}

__device__ __forceinline__ u16 f2bf(float f) {
    unsigned int x = __float_as_uint(f);
    unsigned int lsb = (x >> 16) & 1u;
    x += 0x7fffu + lsb;              // round-to-nearest-even
    return (u16)(x >> 16);
}

__device__ __forceinline__ float sigmoidf_(float x) {
    return 1.0f / (1.0f + expf(-x));
}

template <bool BF>
__device__ __forceinline__ float ldv(const void* p, size_t i) {
    if (BF) return bf2f(((const u16*)p)[i]);
    return ((const float*)p)[i];
}
__device__ __forceinline__ float ldvf(int flag, const void* p, size_t i) {
    return flag ? ldv<true>(p, i) : ldv<false>(p, i);
}

// ---------------------------------------------------------------------------
// k_cvt: per-block dtype self-detect + convert/transpose small float tensors
// to fp32 in ws. GRU weights interleaved as wC[k][j][8] = {wih_r,wih_z,wih_n,
// whh_r,whh_z,whh_n,pad,pad}. Also zero-inits the SD panel region.
template <bool BF>
__device__ void cvt_impl(int t,
                         const void* ew, const void* ggc, const void* wih, const void* whh,
                         const void* bih, const void* bhh, const void* W1w, const void* W1b,
                         const void* W2w, const void* W2b, const void* Wtw, const void* Wtb,
                         const void* qw, const void* qb, const void* W3w, const void* W3b,
                         float* __restrict__ W) {
    const void* src; int si; int doff; int di;
    if      (t <   2048) { src = ew;  si = t;          doff = 0;      di = si; }
    else if (t <  12048) { src = ggc; si = t - 2048;   doff = 2048;   di = si; }                      // row-major (k_gm)
    else if (t <  42048) { src = wih; si = t - 12048;  doff = 12048;  { int r = si / 100, k = si - r * 100; di = k * 800 + (r % 100) * 8 + r / 100; } }
    else if (t <  72048) { src = whh; si = t - 42048;  doff = 12048;  { int r = si / 100, k = si - r * 100; di = k * 800 + (r % 100) * 8 + 3 + r / 100; } }
    else if (t <  72348) { src = bih; si = t - 72048;  doff = 92048;  di = si; }
    else if (t <  72648) { src = bhh; si = t - 72348;  doff = 92352;  di = si; }
    else if (t <  82648) { src = W1w; si = t - 72648;  doff = 92656;  di = (si % 100) * 100 + si / 100; }   // T
    else if (t <  82748) { src = W1b; si = t - 82648;  doff = 102656; di = si; }
    else if (t <  92748) { src = W2w; si = t - 82748;  doff = 102768; di = (si % 100) * 100 + si / 100; }   // T
    else if (t <  92848) { src = W2b; si = t - 92748;  doff = 112768; di = si; }
    else if (t < 102848) { src = Wtw; si = t - 92848;  doff = 112880; di = (si % 100) * 100 + si / 100; }   // T
    else if (t < 102948) { src = Wtb; si = t - 102848; doff = 122880; di = si; }
    else if (t < 103048) { src = qw;  si = t - 102948; doff = 122992; di = si; }
    else if (t < 103049) { src = qb;  si = t - 103048; doff = 123104; di = si; }
    else if (t < 123049) { src = W3w; si = t - 103049; doff = 123120; di = (si % 200) * 100 + si / 200; }   // T
    else                 { src = W3b; si = t - 123049; doff = 143120; di = si; }
    W[doff + di] = ldv<BF>(src, si);
}

__global__ void __launch_bounds__(256) k_cvt(const void* embed_raw, int* __restrict__ flag,
                      const void* ew, const void* ggc, const void* wih, const void* whh,
                      const void* bih, const void* bhh, const void* W1w, const void* W1b,
                      const void* W2w, const void* W2b, const void* Wtw, const void* Wtb,
                      const void* qw, const void* qb, const void* W3w, const void* W3b,
                      float* __restrict__ W, u16* __restrict__ SD) {
    __shared__ int cnt;
    if (threadIdx.x == 0) cnt = 0;
    __syncthreads();
    int bad = 0;
    const u16* eb = (const u16*)embed_raw;
    for (int i = threadIdx.x; i < 4096; i += 256) {
        float v = bf2f(eb[i]);
        if (!(fabsf(v) <= 0.5f)) bad++;   // counts NaN too
    }
    if (bad) atomicAdd(&cnt, bad);
    __syncthreads();
    const bool bf = (cnt == 0);
    if (blockIdx.x == 0 && threadIdx.x == 0) flag[0] = bf ? 1 : 0;
    int t = blockIdx.x * 256 + threadIdx.x;
    if (t < 4096) ((unsigned int*)SD)[t] = 0u;   // zero SD panels (8192 u16)
    if (t >= 123149) return;
    if (bf) cvt_impl<true >(t, ew, ggc, wih, whh, bih, bhh, W1w, W1b, W2w, W2b, Wtw, Wtb, qw, qb, W3w, W3b, W);
    else    cvt_impl<false>(t, ew, ggc, wih, whh, bih, bhh, W1w, W1b, W2w, W2b, Wtw, Wtb, qw, qb, W3w, W3b, W);
}

// ---------------------------------------------------------------------------
// k_ecvt: one-time embed -> padded bf16 (row stride EBS=104, cols 100..103=0).
// One extra guard row (r == NNODE) zeroed: k_score's ks=3/quad>=1 B-frag loads
// over-read up to 24 u16 past the last row (multiplied by zero A, but must be
// finite). Each thread writes one u32 (2 cols).
__global__ void __launch_bounds__(256) k_ecvt(const int* __restrict__ flag,
                                              const void* __restrict__ embed,
                                              u16* __restrict__ EB) {
    const bool bf = (flag[0] != 0);
    int t = blockIdx.x * 256 + threadIdx.x;
    const int total = (NNODE + 1) * (EBS / 2);
    if (t >= total) return;
    int r = t / (EBS / 2), c2 = t - r * (EBS / 2);
    int k0 = c2 * 2;
    unsigned int w = 0;
    if (r < NNODE && k0 + 1 < Hh) {
        if (bf) {
            w = *(const unsigned int*)&((const u16*)embed)[(size_t)r * Hh + k0];
        } else {
            float2 e2 = *(const float2*)&((const float*)embed)[(size_t)r * Hh + k0];
            w = (unsigned int)f2bf(e2.x) | ((unsigned int)f2bf(e2.y) << 16);
        }
    }
    ((unsigned int*)EB)[t] = w;
}

// ---------------------------------------------------------------------------
// k_gm: fused embed-gather + m = h0 @ ggc, plus agg zero-init.
__global__ void __launch_bounds__(256) k_gm(const int* __restrict__ flag,
                                            const int* __restrict__ x,
                                            const void* __restrict__ embed,
                                            const float* __restrict__ ggc_w,
                                            float* __restrict__ m,
                                            float* __restrict__ agg) {
    __shared__ float W[Hh * Hh];
    __shared__ float H[8 * Hh];
    const int tid = threadIdx.x;
    const int fl = flag[0];
    const int r0 = blockIdx.x * 8;
    for (int idx = tid; idx < Hh * Hh; idx += 256) W[idx] = ggc_w[idx];
    for (int idx = tid; idx < 8 * Hh; idx += 256) {
        int i = idx / Hh, j = idx - i * Hh;
        H[idx] = ldvf(fl, embed, (size_t)x[r0 + i] * Hh + j);
    }
    for (int idx = tid; idx < 8 * Hh; idx += 256) agg[r0 * Hh + idx] = 0.0f;
    __syncthreads();
    for (int idx = tid; idx < 8 * Hh; idx += 256) {
        int i = idx / Hh, j = idx - i * Hh;
        float acc = 0.0f;
#pragma unroll 4
        for (int k = 0; k < Hh; ++k) acc += H[i * Hh + k] * W[k * Hh + j];
        m[(r0 + i) * Hh + j] = acc;
    }
}

// agg[dst[e]] += ew[e] * m[src[e]]
__global__ void k_scatter(const int* __restrict__ ei, const float* __restrict__ ew,
                          const float* __restrict__ m, float* __restrict__ agg) {
    int t = blockIdx.x * 256 + threadIdx.x;
    if (t >= EE * Hh) return;
    int e = t / Hh, j = t - e * Hh;
    int src = ei[e], dst = ei[EE + e];
    atomicAdd(&agg[dst * Hh + j], ew[e] * m[src * Hh + j]);
}

// ---------------------------------------------------------------------------
// k_gruatt: GRU cell fused with the heavy attention matmuls. 256 blocks x
// GRB=4 session rows (4 rows always within one session b). agg/h0/h1 staged
// in LDS (replaces per-thread scalar gathers). Phase 2 computes Q2 = h1@W2T+b
// and VTs = h1@WtT+b for the same rows; blocks owning a session-final row
// also emit Q1[b] = s_l@W1T+b.
__global__ void __launch_bounds__(256) k_gruatt(const int* __restrict__ flag,
                      const int* __restrict__ x, const void* __restrict__ embed,
                      const float* __restrict__ agg, const float* __restrict__ wC,
                      const float* __restrict__ bih, const float* __restrict__ bhh,
                      const float* __restrict__ W1T, const float* __restrict__ W1b,
                      const float* __restrict__ W2T, const float* __restrict__ W2b,
                      const float* __restrict__ WtT, const float* __restrict__ Wtb,
                      float* __restrict__ h1, float* __restrict__ Q2g,
                      float* __restrict__ VTg, float* __restrict__ Q1g) {
    __shared__ float sA[GRB * Hh];
    __shared__ float sH0[GRB * Hh];
    __shared__ float sV[GRB * Hh];
    const int tid = threadIdx.x;
    const int r0 = blockIdx.x * GRB;
    const int fl = flag[0];
    for (int o = tid; o < GRB * Hh; o += 256) {
        int i = o / Hh, j = o - i * Hh;
        sA[o] = agg[(r0 + i) * Hh + j];
        sH0[o] = ldvf(fl, embed, (size_t)x[r0 + i] * Hh + j);
    }
    __syncthreads();
    for (int o = tid; o < GRB * Hh; o += 256) {
        int i = o / Hh, j = o - i * Hh;
        float s_ir = bih[j], s_iz = bih[j + Hh], s_in = bih[j + 2 * Hh];
        float s_hr = bhh[j], s_hz = bhh[j + Hh], s_hn = bhh[j + 2 * Hh];
        const float* ai = sA + i * Hh;
        const float* hi = sH0 + i * Hh;
        const float* wbase = wC + j * 8;
        for (int k = 0; k < Hh; ++k) {
            float a = ai[k], h = hi[k];
            const float* wr = wbase + k * 800;
            float4 w0 = *(const float4*)wr;
            float2 w1 = *(const float2*)(wr + 4);
            s_ir += a * w0.x;
            s_iz += a * w0.y;
            s_in += a * w0.z;
            s_hr += h * w0.w;
            s_hz += h * w1.x;
            s_hn += h * w1.y;
        }
        float r = sigmoidf_(s_ir + s_hr);
        float z = sigmoidf_(s_iz + s_hz);
        float n = tanhf(s_in + r * s_hn);
        float hv = (1.0f - z) * n + z * hi[j];
        sV[o] = hv;
        h1[(r0 + i) * Hh + j] = hv;
    }
    __syncthreads();
    for (int o = tid; o < GRB * Hh; o += 256) {
        int i = o / Hh, j = o - i * Hh;
        const float* vi = sV + i * Hh;
        float a2 = 0.0f, at = 0.0f;
        for (int k = 0; k < Hh; ++k) {
            float vk = vi[k];
            a2 += vk * W2T[k * Hh + j];
            at += vk * WtT[k * Hh + j];
        }
        Q2g[(r0 + i) * Hh + j] = a2 + W2b[j];
        VTg[(r0 + i) * Hh + j] = at + Wtb[j];
    }
    if ((r0 & 15) == 12 && tid < Hh) {
        const float* vl = sV + 3 * Hh;       // global row r0+3 == session-final
        float a1 = 0.0f;
        for (int k = 0; k < Hh; ++k) a1 += vl[k] * W1T[k * Hh + tid];
        Q1g[(r0 >> 4) * Hh + tid] = a1 + W1b[tid];
    }
}

// ---------------------------------------------------------------------------
// k_att2: light per-session tail — alpha (16x16-thread shfl-reduce), s_g,
// s_h, swizzled P panel + SD row writes. One block per b.
__global__ void __launch_bounds__(256) k_att2(const float* __restrict__ h1,
                    const float* __restrict__ Q1g, const float* __restrict__ Q2g,
                    const float* __restrict__ VTg,
                    const float* __restrict__ qw, const float* __restrict__ qb,
                    const float* __restrict__ W3T, const float* __restrict__ W3b,
                    u16* __restrict__ P, u16* __restrict__ SD) {
    __shared__ float V[LL * Hh];
    __shared__ float VTs[LL * Hh];
    __shared__ float AL[LL];
    __shared__ float SG[Hh];
    __shared__ float SH[Hh];
    const int b = blockIdx.x, tid = threadIdx.x;
    for (int o = tid; o < LL * Hh; o += 256) {
        V[o] = h1[b * LL * Hh + o];
        VTs[o] = VTg[b * LL * Hh + o];
    }
    __syncthreads();
    {
        // alpha: 16 l-rows x 16 threads each; partials reduced via shfl
        // (threads of one l are 16 consecutive lanes).
        int l = tid >> 4, t = tid & 15;
        float acc = 0.0f;
        for (int j = t; j < Hh; j += 16)
            acc += sigmoidf_(Q1g[b * Hh + j] + Q2g[(b * LL + l) * Hh + j]) * qw[j];
        acc += __shfl_xor(acc, 8);
        acc += __shfl_xor(acc, 4);
        acc += __shfl_xor(acc, 2);
        acc += __shfl_xor(acc, 1);
        if (t == 0) AL[l] = acc + qb[0];
    }
    __syncthreads();
    if (tid < Hh) {
        float acc = 0.0f;
#pragma unroll
        for (int l = 0; l < LL; ++l) acc += AL[l] * V[l * Hh + tid];
        SG[tid] = acc;
    }
    __syncthreads();
    if (tid < Hh) {
        float acc = W3b[tid];
        for (int k = 0; k < Hh; ++k) acc += V[(LL - 1) * Hh + k] * W3T[k * Hh + tid];
        for (int k = 0; k < Hh; ++k) acc += SG[k] * W3T[(Hh + k) * Hh + tid];
        SH[tid] = acc;
    }
    __syncthreads();
    // Swizzled P write: 8 frags x 64 lanes x 8 elems
    for (int w = tid; w < PFR * 64; w += 256) {
        int f = w >> 6, lane = w & 63;
        int t = f >> 2, ks = f & 3;
        int mm = lane & 15, qq = lane >> 4;
        int col0 = ks * 32 + qq * 8;
        short8 t8;
#pragma unroll
        for (int e = 0; e < 8; ++e) {
            int col = col0 + e;
            float v = 0.0f;
            if (col < Hh) v = (t == 0) ? VTs[mm * Hh + col] : V[mm * Hh + col];
            t8[e] = (short)f2bf(v);
        }
        *(short8*)&P[((size_t)b * PFR + f) * 512 + lane * 8] = t8;
    }
    // SD write: A-tile row (b&15) of slice (b>>4); 128 u16 scattered.
    if (tid < 128) {
        int ks = tid >> 5, qq = (tid >> 3) & 3, e = tid & 7;
        int col = ks * 32 + qq * 8 + e;
        float v = (col < Hh) ? SH[col] : 0.0f;
        SD[(((size_t)(b >> 4) * 4 + ks) * 64 + qq * 16 + (b & 15)) * 8 + e] = f2bf(v);
    }
}

// ---------------------------------------------------------------------------
// k_score v8: BSPL=4 (16-deep b-loop) halves embed/EB traffic vs v7; SD tile's
// 16 rows map 1:1 onto the 16 b's of a slice. GJ=4 j-groups per wave, padded
// bf16 EB fragment loads (EMODE 1), register prefetch of next P panel over
// compute, one barrier per iter, max-free softmax.
__device__ __forceinline__ short8 load_efrag(const void* embed, bool bf, int j, int k0) {
    short8 v = {0, 0, 0, 0, 0, 0, 0, 0};
    if (j >= NNODE || k0 >= Hh) return v;
    if (bf) {
        const u16* row = (const u16*)embed + (size_t)j * Hh + k0;
        if (k0 + 8 <= Hh) {
            ushort4 a = *(const ushort4*)(row);
            ushort4 b = *(const ushort4*)(row + 4);
            v[0] = (short)a.x; v[1] = (short)a.y; v[2] = (short)a.z; v[3] = (short)a.w;
            v[4] = (short)b.x; v[5] = (short)b.y; v[6] = (short)b.z; v[7] = (short)b.w;
        } else {
            for (int e = 0; e < Hh - k0; ++e) v[e] = (short)row[e];
        }
    } else {
        const float* row = (const float*)embed + (size_t)j * Hh + k0;
        if (k0 + 8 <= Hh) {
            float4 a = *(const float4*)(row);
            float4 b = *(const float4*)(row + 4);
            v[0] = (short)f2bf(a.x); v[1] = (short)f2bf(a.y); v[2] = (short)f2bf(a.z); v[3] = (short)f2bf(a.w);
            v[4] = (short)f2bf(b.x); v[5] = (short)f2bf(b.y); v[6] = (short)f2bf(b.z); v[7] = (short)f2bf(b.w);
        } else {
            for (int e = 0; e < Hh - k0; ++e) v[e] = (short)f2bf(row[e]);
        }
    }
    return v;
}

template <int EMODE>
__global__ void __launch_bounds__(256) k_score(const int* __restrict__ flag,
                                               const void* __restrict__ embed,
                                               const u16* __restrict__ EB,
                                               const u16* __restrict__ P,
                                               const u16* __restrict__ SD,
                                               void* __restrict__ out) {
    __shared__ alignas(16) u16 sPan[2][PPAN];    // 2 x 8192 B
    const int jb = blockIdx.x * 256;
    const int slice = blockIdx.y;
    const int b0 = slice * BPB;
    const int tid = threadIdx.x;
    const bool bf = (flag[0] != 0);
    const int wave = tid >> 6, lane = tid & 63;
    const int m = lane & 15, quad = lane >> 4;

    // B fragments: 4 groups of 16 embed rows per wave, loaded once.
    short8 Bf[GJ][4];
#pragma unroll
    for (int g = 0; g < GJ; ++g)
#pragma unroll
        for (int ks = 0; ks < 4; ++ks) {
            int j = jb + wave * 64 + g * 16 + m;
            if (EMODE) {
                short8 v = {0, 0, 0, 0, 0, 0, 0, 0};
                if (j < NNODE)
                    v = *(const short8*)&EB[(size_t)j * EBS + ks * 32 + quad * 8];
                Bf[g][ks] = v;
            } else {
                Bf[g][ks] = load_efrag(embed, bf, j, ks * 32 + quad * 8);
            }
        }

    // SD prologue: sd[b0+r][j] for all 16 b's of this slice, 16 MFMAs total.
    short8 Sf[4];
#pragma unroll
    for (int ks = 0; ks < 4; ++ks)
        Sf[ks] = *(const short8*)&SD[(((size_t)slice * 4 + ks) * 64 + lane) * 8];
    f32x4 accsd[GJ];
#pragma unroll
    for (int g = 0; g < GJ; ++g) {
        accsd[g] = (f32x4){0.0f, 0.0f, 0.0f, 0.0f};
#pragma unroll
        for (int ks = 0; ks < 4; ++ks)
            accsd[g] = __builtin_amdgcn_mfma_f32_16x16x32_bf16(Sf[ks], Bf[g][ks], accsd[g], 0, 0, 0);
    }

    // Preload panel b0 -> LDS buffer 0 (512 uint4)
    {
        const uint4* s4 = (const uint4*)(P + (size_t)b0 * PPAN);
        uint4 g0 = s4[tid], g1 = s4[tid + 256];
        uint4* d = (uint4*)sPan[0];
        d[tid] = g0; d[tid + 256] = g1;
    }
    __syncthreads();

    int cur = 0;
    for (int bi = 0; bi < BPB; ++bi) {
        const int b = b0 + bi;
        // Issue next-panel global loads (no wait — overlaps compute below)
        uint4 g0, g1;
        if (bi + 1 < BPB) {
            const uint4* s4 = (const uint4*)(P + (size_t)(b + 1) * PPAN);
            g0 = s4[tid]; g1 = s4[tid + 256];
        }

        const u16* sp = sPan[cur];
        f32x4 acc[GJ][2];
#pragma unroll
        for (int g = 0; g < GJ; ++g)
#pragma unroll
            for (int t = 0; t < 2; ++t)
                acc[g][t] = (f32x4){0.0f, 0.0f, 0.0f, 0.0f};
#pragma unroll
        for (int t = 0; t < 2; ++t) {
            short8 A0 = *(const short8*)&sp[(t * 4 + 0) * 512 + lane * 8];
            short8 A1 = *(const short8*)&sp[(t * 4 + 1) * 512 + lane * 8];
            short8 A2 = *(const short8*)&sp[(t * 4 + 2) * 512 + lane * 8];
            short8 A3 = *(const short8*)&sp[(t * 4 + 3) * 512 + lane * 8];
#pragma unroll
            for (int g = 0; g < GJ; ++g) {
                acc[g][t] = __builtin_amdgcn_mfma_f32_16x16x32_bf16(A0, Bf[g][0], acc[g][t], 0, 0, 0);
                acc[g][t] = __builtin_amdgcn_mfma_f32_16x16x32_bf16(A1, Bf[g][1], acc[g][t], 0, 0, 0);
                acc[g][t] = __builtin_amdgcn_mfma_f32_16x16x32_bf16(A2, Bf[g][2], acc[g][t], 0, 0, 0);
                acc[g][t] = __builtin_amdgcn_mfma_f32_16x16x32_bf16(A3, Bf[g][3], acc[g][t], 0, 0, 0);
            }
        }

        // Epilogue (max-free softmax). C/D layout: col=lane&15 (embed row
        // within group), row=quad*4+reg (P row) — m89/m91-verified.
#pragma unroll
        for (int g = 0; g < GJ; ++g) {
            float den = 0.0f, num = 0.0f;
#pragma unroll
            for (int r = 0; r < 4; ++r) {
                float p = __expf(acc[g][0][r]);
                den += p;
                num += p * acc[g][1][r];
            }
            den += __shfl_xor(den, 16); num += __shfl_xor(num, 16);
            den += __shfl_xor(den, 32); num += __shfl_xor(num, 32);
            // sd for (b, j=...+m) sits in lane (bi>>2)*16+m, reg bi&3.
            f32x4 s4v = accsd[g];
            int rr = bi & 3;
            float sdv = (rr == 0) ? s4v[0] : (rr == 1) ? s4v[1] : (rr == 2) ? s4v[2] : s4v[3];
            sdv = __shfl(sdv, ((bi >> 2) << 4) | m);
            if (quad == 0) {
                int j = jb + wave * 64 + g * 16 + m;
                if (j < NNODE) {
                    float z = sdv + num / den;
                    if (bf) ((u16*)out)[(size_t)b * NNODE + j] = f2bf(z);
                    else    ((float*)out)[(size_t)b * NNODE + j] = z;
                }
            }
        }

        // Commit prefetched panel to the other buffer (vmcnt wait lands here,
        // after compute) then single barrier.
        if (bi + 1 < BPB) {
            uint4* d = (uint4*)sPan[cur ^ 1];
            d[tid] = g0; d[tid + 256] = g1;
        }
        __syncthreads();
        cur ^= 1;
    }
}

extern "C" void kernel_launch(void* const* d_in, const int* in_sizes, int n_in,
                              void* d_out, int out_size, void* d_ws, size_t ws_size,
                              hipStream_t stream) {
    const int* x      = (const int*)d_in[0];
    const int* ei     = (const int*)d_in[1];
    const void* ew    = d_in[2];
    // d_in[3] batch: unused by reference
    const void* embed = d_in[4];
    const void* ggc   = d_in[5];
    const void* wih   = d_in[6];
    const void* whh   = d_in[7];
    const void* bih   = d_in[8];
    const void* bhh   = d_in[9];
    const void* W1w   = d_in[10];
    const void* W1b   = d_in[11];
    const void* W2w   = d_in[12];
    const void* W2b   = d_in[13];
    const void* Wtw   = d_in[14];
    const void* Wtb   = d_in[15];
    const void* qw    = d_in[16];
    const void* qb    = d_in[17];
    const void* W3w   = d_in[18];
    const void* W3b   = d_in[19];
    float* ws = (float*)d_ws;
    int* flag = (int*)d_ws;          // ws[0]

    // ws layout (floats):
    //   [0..64)              flag + pad
    //   [64..64+143232)      fp32 weight region W (see cvt_impl offsets)
    //   D = ws+143296, data region:
    //     m    = D+0       (102400)  written k_gm, read k_scatter (dead after)
    //     agg  = D+102400  (102400)  zeroed k_gm, scatter-add, read k_gruatt
    //     h1   = D+0       (102400)  overlays dead m; k_gruatt -> k_att2
    //     Q2g  = D+204800  (102400)
    //     VTg  = D+307200  (102400)
    //     Q1g  = D+409600  (6400)
    //     P    = (u16*)(D+416000)  131072 fl  (written k_att2)
    //     SD   = (u16*)(D+547072)  4096 fl    (zeroed k_cvt, written k_att2)
    //     EB   = (u16*)(D+551168)  2080052 fl padded bf16 embed + guard row
    float* W = ws + 64;
    float* ew_f  = W + 0;
    float* ggc_f = W + 2048;
    float* wC    = W + 12048;
    float* bih_f = W + 92048;
    float* bhh_f = W + 92352;
    float* W1T   = W + 92656;
    float* W1b_f = W + 102656;
    float* W2T   = W + 102768;
    float* W2b_f = W + 112768;
    float* WtT   = W + 112880;
    float* Wtb_f = W + 122880;
    float* qw_f  = W + 122992;
    float* qb_f  = W + 123104;
    float* W3T   = W + 123120;
    float* W3b_f = W + 143120;

    float* D     = ws + 143296;
    float* m     = D;
    float* agg   = D + 102400;
    float* h1    = D;                       // overlays dead m
    float* Q2g   = D + 204800;
    float* VTg   = D + 307200;
    float* Q1g   = D + 409600;
    u16*   P     = (u16*)(D + 416000);
    u16*   SDp   = (u16*)(D + 547072);
    u16*   EB    = (u16*)(D + 551168);

    const size_t need_bytes = (size_t)(143296 + 551168) * 4 + (size_t)(NNODE + 1) * EBS * 2;
    const bool emode = (ws_size >= need_bytes);

    k_cvt    <<<dim3(482), dim3(256), 0, stream>>>(embed, flag, ew, ggc, wih, whh, bih, bhh,
                                                   W1w, W1b, W2w, W2b, Wtw, Wtb, qw, qb, W3w, W3b, W, SDp);
    if (emode)
        k_ecvt<<<dim3(((NNODE + 1) * (EBS / 2) + 255) / 256), dim3(256), 0, stream>>>(flag, embed, EB);
    k_gm     <<<dim3(128), dim3(256), 0, stream>>>(flag, x, embed, ggc_f, m, agg);
    k_scatter<<<dim3(800), dim3(256), 0, stream>>>(ei, ew_f, m, agg);
    k_gruatt <<<dim3(NN / GRB), dim3(256), 0, stream>>>(flag, x, embed, agg, wC, bih_f, bhh_f,
                                                        W1T, W1b_f, W2T, W2b_f, WtT, Wtb_f,
                                                        h1, Q2g, VTg, Q1g);
    k_att2   <<<dim3(BB), dim3(256), 0, stream>>>(h1, Q1g, Q2g, VTg, qw_f, qb_f, W3T, W3b_f, P, SDp);
    if (emode)
        k_score<1><<<dim3((NNODE + 255) / 256, BSPL), dim3(256), 0, stream>>>(flag, embed, EB, P, SDp, d_out);
    else
        k_score<0><<<dim3((NNODE + 255) / 256, BSPL), dim3(256), 0, stream>>>(flag, embed, EB, P, SDp, d_out);
}